// Round 2
// baseline (2099.437 us; speedup 1.0000x reference)
//
#include <hip/hip_runtime.h>

// MonoFlangerChorusModule: feedback delay line with modulated fractional tap.
// Round 1: chunked wave-parallel recurrence. One wave per (batch, channel)
// chain. Each iteration, lane j proposes step s0+j; ballot finds the longest
// valid prefix K (all reads strictly pre-chunk), lanes < K compute and write
// in parallel. Progress >= 1 step/iter guaranteed (eff >= 1 always).

constexpr int MAX_MIN = 441;   // int(10/1000*44100 + 0.5)
constexpr int MAX_LFO = 441;
constexpr int D = MAX_MIN + MAX_LFO;   // 882
constexpr int B = 32;
constexpr int C = 2;
constexpr int N = 65536;

__global__ __launch_bounds__(64)
void flanger_chunked(const float* __restrict__ x,        // (B,C,N)
                     const float* __restrict__ mod_sig,  // (B,N)
                     const float* __restrict__ feedback, // (B,)
                     const float* __restrict__ mdwp,     // (B,)
                     const float* __restrict__ widthp,   // (B,)
                     const float* __restrict__ depthp,   // (B,)
                     const float* __restrict__ mixp,     // (B,)
                     float* __restrict__ out)            // (B,C,N)
{
  const int bc   = blockIdx.x;        // 0..63 = b*C + c
  const int b    = bc >> 1;
  const int lane = threadIdx.x;       // 0..63

  // Delay buffer + mirror slot (buf[D] duplicates buf[0] so the p==881
  // neighbor read is branch-free) + 1 pad.
  __shared__ float buf[D + 2];
  for (int i = lane; i < D + 2; i += 64) buf[i] = 0.0f;
  __syncthreads();

  const float fb     = feedback[b];
  const float dpv    = depthp[b];
  const float mx     = mixp[b];
  const float wscale = (float)MAX_LFO * widthp[b];  // (441*width)
  const float dmin   = mdwp[b] * (float)MAX_MIN;    // mdw*441

  const float* __restrict__ xc = x + (size_t)bc * N;
  const float* __restrict__ ms = mod_sig + (size_t)b * N;
  float* __restrict__ oc = out + (size_t)bc * N;

  int s0 = 0;   // next step to retire
  int w0 = 0;   // s0 % D, maintained incrementally
  while (s0 < N) {
    const int s = s0 + lane;
    const bool in = (s < N);
    const float mv = in ? ms[s] : 0.0f;
    const float xv = in ? xc[s] : 0.0f;

    int wi = w0 + lane;
    if (wi >= D) wi -= D;                 // lane < 64, w0 < D -> wi < D+64 < 2D

    // read index, matching reference float ops exactly
    const float delay = wscale * mv + dmin;            // in [0, 882)
    float r = (float)wi - delay + (float)D;            // in (wi, wi+882]
    if (r >= (float)D) r -= (float)D;                  // == fmod (exact)
    const float pf = floorf(r);
    const int   p  = (int)pf;                          // 0..881
    const float f  = r - pf;

    // dependency distance: slot q last written dist steps ago
    int dist = wi - p;
    if (dist <= 0) dist += D;                          // dist(p) in [1, D]
    const int eff = (dist == 1) ? 1 : (dist - 1);      // min over {p, p+1}

    const bool valid = in && (eff > lane);
    const unsigned long long bad = __ballot(!valid);
    const int K = bad ? (int)(__ffsll((long long)bad) - 1) : 64;

    if (lane < K) {
      const float pv = buf[p];
      const float nv = buf[p + 1];        // p==881 -> mirror slot
      const float interp = f * nv + (1.0f - f) * pv;
      const float y = xv + fb * interp;
      buf[wi] = y;                        // same-wave DS ops are in-order:
      if (wi == 0) buf[D] = y;            // reads above see pre-chunk state
      const float o = xv + dpv * interp;
      float res = (1.0f - mx) * xv + mx * o;
      res = fminf(fmaxf(res, -1.0f), 1.0f);
      oc[s] = res;
    }

    s0 += K;
    w0 += K;
    if (w0 >= D) w0 -= D;
  }
}

extern "C" void kernel_launch(void* const* d_in, const int* in_sizes, int n_in,
                              void* d_out, int out_size, void* d_ws, size_t ws_size,
                              hipStream_t stream) {
  const float* x        = (const float*)d_in[0];
  const float* mod_sig  = (const float*)d_in[1];
  const float* feedback = (const float*)d_in[2];
  const float* mdw      = (const float*)d_in[3];
  const float* width    = (const float*)d_in[4];
  const float* depth    = (const float*)d_in[5];
  const float* mix      = (const float*)d_in[6];
  float* out = (float*)d_out;

  flanger_chunked<<<dim3(B * C), dim3(64), 0, stream>>>(
      x, mod_sig, feedback, mdw, width, depth, mix, out);
}

// Round 3
// 1034.879 us; speedup vs baseline: 2.0287x; 2.0287x over previous
//
#include <hip/hip_runtime.h>

// MonoFlangerChorusModule — round 2: chunked wave-parallel recurrence with
// fully precomputed per-step metadata. One wave per (batch,channel) chain.
// Per tile: parallel phase packs {p|wi, frac, x, eff} into LDS float4 q[];
// serial phase walks chunks with the ballot chain (next-chunk K from
// precomputed eff) overlapped against the buf read->fma->write chain.

constexpr int MAX_MIN = 441;   // int(10/1000*44100 + 0.5)
constexpr int MAX_LFO = 441;
constexpr int D = MAX_MIN + MAX_LFO;   // 882
constexpr int B = 32;
constexpr int C = 2;
constexpr int N = 65536;
constexpr int T = 2048;                // tile length (power of 2)
constexpr int NT = N / T;              // 32 tiles

__global__ __launch_bounds__(64)
void flanger_pf(const float* __restrict__ x,        // (B,C,N)
                const float* __restrict__ mod_sig,  // (B,N)
                const float* __restrict__ feedback, // (B,)
                const float* __restrict__ mdwp,     // (B,)
                const float* __restrict__ widthp,   // (B,)
                const float* __restrict__ depthp,   // (B,)
                const float* __restrict__ mixp,     // (B,)
                float* __restrict__ out)            // (B,C,N)
{
  const int bc   = blockIdx.x;        // b*C + c
  const int b    = bc >> 1;
  const int lane = threadIdx.x;       // 0..63

  // Delay buffer + mirror slot (buf[D] duplicates buf[0]) + pad.
  __shared__ float buf[D + 2];
  // Per-step metadata: {as_float(p | wi<<10), frac, x, (float)eff}.
  // 64 pad entries with eff=0 force chunks to end at the tile boundary.
  __shared__ float4 q[T + 64];

  for (int i = lane; i < D + 2; i += 64) buf[i] = 0.0f;
  q[T + lane] = make_float4(0.0f, 0.0f, 0.0f, 0.0f);
  __syncthreads();

  const float fb     = feedback[b];
  const float dpv    = depthp[b];
  const float mx     = mixp[b];
  const float wscale = (float)MAX_LFO * widthp[b];  // 441*width
  const float dmin   = mdwp[b] * (float)MAX_MIN;    // mdw*441

  const float* __restrict__ xc = x + (size_t)bc * N;
  const float* __restrict__ ms = mod_sig + (size_t)b * N;
  float* __restrict__ oc = out + (size_t)bc * N;

  for (int t = 0; t < NT; ++t) {
    const int tbase = t * T;

    // ---- Phase 1 (parallel): precompute metadata for this tile ----
#pragma unroll 4
    for (int rr = 0; rr < T / 64; ++rr) {
      const int i = rr * 64 + lane;
      const int s = tbase + i;
      const float mv = ms[s];
      const float xv = xc[s];
      const float delay = wscale * mv + dmin;        // [0, 882)
      const int   wi = s % D;
      float r = (float)wi - delay + (float)D;        // (0, 2D)
      if (r >= (float)D) r -= (float)D;              // exact == fmod here
      const float pf = floorf(r);
      const int   p  = (int)pf;                      // 0..881
      const float f  = r - pf;
      int dist = wi - p;
      if (dist <= 0) dist += D;                      // steps since slot p written
      const int eff = (dist == 1) ? 1 : (dist - 1);  // min over {p, p+1}, >= 1
      q[i] = make_float4(__int_as_float(p | (wi << 10)), f, xv, (float)eff);
    }
    // Single wave: program order guarantees q[] visible to the serial phase.

    // ---- Phase 2 (serial): chunked recurrence ----
    int s0 = tbase;
    float4 qc = q[lane];                              // chunk at s0
    {
      const bool valid = ((float)lane < qc.w);
      const unsigned long long bad = __ballot(!valid);
      // fallthrough K computed below
      int K0 = bad ? (int)__ffsll((long long)bad) - 1 : 64;
      // store in a mutable K
      while (s0 < tbase + T) {
        const int K = K0;
        const int pk = __float_as_int(qc.x);
        const int p  = pk & 1023;
        const int wi = pk >> 10;
        const float f  = qc.y;
        const float xv = qc.z;

        // Speculative reads for ALL lanes (pre-chunk state; reads precede
        // this iteration's writes in program order).
        const float pv = buf[p];
        const float nv = buf[p + 1];                  // p==881 -> mirror

        // Prefetch next chunk's metadata (independent of buf chain).
        const int s1 = s0 + K;
        const float4 qn = q[s1 - tbase + lane];

        const float interp = f * nv + (1.0f - f) * pv;
        const float y = xv + fb * interp;
        if (lane < K) {
          buf[wi] = y;
          if (wi == 0) buf[D] = y;                    // maintain mirror
          const float o = xv + dpv * interp;
          float res = (1.0f - mx) * xv + mx * o;
          res = fminf(fmaxf(res, -1.0f), 1.0f);
          oc[s0 + lane] = res;
        }

        const bool v2 = ((float)lane < qn.w);
        const unsigned long long bad2 = __ballot(!v2);
        K0 = bad2 ? (int)__ffsll((long long)bad2) - 1 : 64;
        s0 = s1;
        qc = qn;
      }
    }
  }
}

extern "C" void kernel_launch(void* const* d_in, const int* in_sizes, int n_in,
                              void* d_out, int out_size, void* d_ws, size_t ws_size,
                              hipStream_t stream) {
  const float* x        = (const float*)d_in[0];
  const float* mod_sig  = (const float*)d_in[1];
  const float* feedback = (const float*)d_in[2];
  const float* mdw      = (const float*)d_in[3];
  const float* width    = (const float*)d_in[4];
  const float* depth    = (const float*)d_in[5];
  const float* mix      = (const float*)d_in[6];
  float* out = (float*)d_out;

  flanger_pf<<<dim3(B * C), dim3(64), 0, stream>>>(
      x, mod_sig, feedback, mdw, width, depth, mix, out);
}